// Round 1
// baseline (307.652 us; speedup 1.0000x reference)
//
#include <hip/hip_runtime.h>
#include <math.h>

#define N_HALF 2048
#define M_TOT  4096
#define D_DIM  256
#define K2     512      // fused K dimension (2*D)

#define BM 64
#define BN 64
#define BK 32
#define CS 8            // column chunks (each wg handles M/CS = 512 columns)
#define LDS_S 68        // padded stride for [BK][BM] LDS tiles (keeps float4 alignment, spreads banks)

// ---------------------------------------------------------------------------
// Kernel 1: build fused GEMM operands + per-row scalars
//   A[i] = [mu^2+var (256) , -2*mu (256)]
//   B[j] = [1/var (256)    , mu/var (256)]
//   slv[i] = sum_d log(var),  cvec[i] = sum_d mu^2/var
// ---------------------------------------------------------------------------
__global__ __launch_bounds__(256) void prep_kernel(
        const float* __restrict__ loc1, const float* __restrict__ scale1,
        const float* __restrict__ loc2, const float* __restrict__ scale2,
        float* __restrict__ A, float* __restrict__ B,
        float* __restrict__ slv, float* __restrict__ cvec) {
    int i = blockIdx.x;
    int d = threadIdx.x;
    float mu, var;
    if (i < N_HALF) { mu = loc1[i * D_DIM + d];            var = scale1[i * D_DIM + d]; }
    else            { mu = loc2[(i - N_HALF) * D_DIM + d]; var = scale2[(i - N_HALF) * D_DIM + d]; }
    float iv = 1.0f / var;
    A[i * K2 + d]         = mu * mu + var;
    A[i * K2 + D_DIM + d] = -2.0f * mu;
    B[i * K2 + d]         = iv;
    B[i * K2 + D_DIM + d] = mu * iv;

    float lv = logf(var);
    float cc = mu * mu * iv;
    __shared__ float s1[256], s2[256];
    s1[d] = lv; s2[d] = cc;
    __syncthreads();
    for (int off = 128; off > 0; off >>= 1) {
        if (d < off) { s1[d] += s1[d + off]; s2[d] += s2[d + off]; }
        __syncthreads();
    }
    if (d == 0) { slv[i] = s1[0]; cvec[i] = s2[0]; }
}

// ---------------------------------------------------------------------------
// Kernel 2: fused GEMM (C = A * B^T, K=512) + online logsumexp epilogue.
// Grid: (CS, M/BM). Each wg: BM rows x 512 cols (8 tiles of 64), maintains a
// running (max, sumexp) per row, writes one partial per (row, chunk).
// sim[i,j] = 5*(slv[j] - slv[i] - 256 + dot(A_i,B_j) + cvec[j]); diag skipped.
// ---------------------------------------------------------------------------
__global__ __launch_bounds__(256) void gemm_lse_kernel(
        const float* __restrict__ A, const float* __restrict__ B,
        const float* __restrict__ slv, const float* __restrict__ cvec,
        float* __restrict__ pm, float* __restrict__ ps) {
    __shared__ float As[BK * LDS_S];
    __shared__ float Bs[BK * LDS_S];
    const int t  = threadIdx.x;
    const int bx = blockIdx.x;   // column chunk 0..CS-1
    const int by = blockIdx.y;   // row block 0..M/BM-1
    const int tc = t & 15;       // output col group
    const int tr = t >> 4;       // output row group
    const int r0 = tr * 4;
    const int lr  = t >> 3;      // staging: row 0..31 (and +32)
    const int lc4 = t & 7;       // staging: float4 index within 32-wide k slab

    const int rowbase = by * BM;

    float m[4], s[4], slv_r[4];
    #pragma unroll
    for (int i = 0; i < 4; ++i) { m[i] = -3.0e38f; s[i] = 0.0f; slv_r[i] = slv[rowbase + r0 + i]; }

    for (int tile = 0; tile < 8; ++tile) {
        const int c0 = bx * 512 + tile * BN;
        float acc[4][4];
        #pragma unroll
        for (int i = 0; i < 4; ++i)
            #pragma unroll
            for (int j = 0; j < 4; ++j) acc[i][j] = 0.0f;

        for (int kk = 0; kk < K2; kk += BK) {
            __syncthreads();   // previous LDS consumers done
            float4 av0 = *(const float4*)&A[(rowbase + lr)      * K2 + kk + lc4 * 4];
            float4 av1 = *(const float4*)&A[(rowbase + lr + 32) * K2 + kk + lc4 * 4];
            float4 bv0 = *(const float4*)&B[(c0 + lr)      * K2 + kk + lc4 * 4];
            float4 bv1 = *(const float4*)&B[(c0 + lr + 32) * K2 + kk + lc4 * 4];
            #pragma unroll
            for (int jj = 0; jj < 4; ++jj) {
                As[(lc4 * 4 + jj) * LDS_S + lr]      = ((const float*)&av0)[jj];
                As[(lc4 * 4 + jj) * LDS_S + lr + 32] = ((const float*)&av1)[jj];
                Bs[(lc4 * 4 + jj) * LDS_S + lr]      = ((const float*)&bv0)[jj];
                Bs[(lc4 * 4 + jj) * LDS_S + lr + 32] = ((const float*)&bv1)[jj];
            }
            __syncthreads();
            #pragma unroll
            for (int k = 0; k < BK; ++k) {
                float4 a = *(const float4*)&As[k * LDS_S + r0];
                float4 b = *(const float4*)&Bs[k * LDS_S + tc * 4];
                #pragma unroll
                for (int i = 0; i < 4; ++i)
                    #pragma unroll
                    for (int j = 0; j < 4; ++j)
                        acc[i][j] = fmaf(((const float*)&a)[i], ((const float*)&b)[j], acc[i][j]);
            }
        }

        // online-LSE epilogue over this 64-col tile
        #pragma unroll
        for (int j = 0; j < 4; ++j) {
            const int colg = c0 + tc * 4 + j;
            const float basec = 5.0f * (slv[colg] + cvec[colg] - 256.0f);
            #pragma unroll
            for (int i = 0; i < 4; ++i) {
                const int rowg = rowbase + r0 + i;
                if (rowg == colg) continue;            // diagonal: excluded (NEG_FILL)
                const float simv = basec - 5.0f * slv_r[i] + 5.0f * acc[i][j];
                if (simv > m[i]) { s[i] = s[i] * expf(m[i] - simv) + 1.0f; m[i] = simv; }
                else             { s[i] += expf(simv - m[i]); }
            }
        }
    }

    // reduce (m,s) across the 16 col-groups sharing each row
    __syncthreads();
    float* redm = As;   // reuse LDS (needs 64*16 floats each)
    float* reds = Bs;
    #pragma unroll
    for (int i = 0; i < 4; ++i) { redm[(r0 + i) * 16 + tc] = m[i]; reds[(r0 + i) * 16 + tc] = s[i]; }
    __syncthreads();
    if (t < 64) {
        const int r = t;
        float mm = -3.0e38f, ss = 0.0f;
        for (int k = 0; k < 16; ++k) {
            const float mk = redm[r * 16 + k], sk = reds[r * 16 + k];
            if (mk > mm) { ss = ss * expf(mm - mk) + sk; mm = mk; }
            else         { ss += sk * expf(mk - mm); }
        }
        pm[(rowbase + r) * CS + bx] = mm;
        ps[(rowbase + r) * CS + bx] = ss;
    }
}

// ---------------------------------------------------------------------------
// Kernel 3: per-row finalize. One wave per row: combine CS partials -> lse,
// compute pos dot, loss[i] = lse - sim_pos.
// ---------------------------------------------------------------------------
__global__ __launch_bounds__(256) void finalize_kernel(
        const float* __restrict__ A, const float* __restrict__ B,
        const float* __restrict__ slv, const float* __restrict__ cvec,
        const float* __restrict__ pm, const float* __restrict__ ps,
        float* __restrict__ loss) {
    const int t = threadIdx.x;
    const int wid = t >> 6, lane = t & 63;
    const int i = blockIdx.x * 4 + wid;
    const int j = (i < N_HALF) ? (i + N_HALF) : (i - N_HALF);   // (i - N) mod M

    float4 a0 = *(const float4*)&A[i * K2 + lane * 8];
    float4 a1 = *(const float4*)&A[i * K2 + lane * 8 + 4];
    float4 b0 = *(const float4*)&B[j * K2 + lane * 8];
    float4 b1 = *(const float4*)&B[j * K2 + lane * 8 + 4];
    float d = a0.x * b0.x + a0.y * b0.y + a0.z * b0.z + a0.w * b0.w
            + a1.x * b1.x + a1.y * b1.y + a1.z * b1.z + a1.w * b1.w;
    #pragma unroll
    for (int off = 1; off < 64; off <<= 1) d += __shfl_xor(d, off, 64);

    if (lane == 0) {
        float mm = -3.0e38f, ss = 0.0f;
        for (int k = 0; k < CS; ++k) {
            const float mk = pm[i * CS + k], sk = ps[i * CS + k];
            if (mk > mm) { ss = ss * expf(mm - mk) + sk; mm = mk; }
            else         { ss += sk * expf(mk - mm); }
        }
        const float lse = mm + logf(ss);
        const float simpos = 5.0f * (slv[j] - slv[i] - 256.0f + d + cvec[j]);
        loss[i] = lse - simpos;
    }
}

// ---------------------------------------------------------------------------
// Kernel 4: mean over M rows -> d_out[0]
// ---------------------------------------------------------------------------
__global__ __launch_bounds__(256) void mean_kernel(const float* __restrict__ loss,
                                                   float* __restrict__ out) {
    __shared__ float sm[256];
    const int t = threadIdx.x;
    float acc = 0.0f;
    for (int k = t; k < M_TOT; k += 256) acc += loss[k];
    sm[t] = acc;
    __syncthreads();
    for (int off = 128; off > 0; off >>= 1) {
        if (t < off) sm[t] += sm[t + off];
        __syncthreads();
    }
    if (t == 0) out[0] = sm[0] * (1.0f / (float)M_TOT);
}

// ---------------------------------------------------------------------------
extern "C" void kernel_launch(void* const* d_in, const int* in_sizes, int n_in,
                              void* d_out, int out_size, void* d_ws, size_t ws_size,
                              hipStream_t stream) {
    const float* loc1   = (const float*)d_in[0];
    const float* scale1 = (const float*)d_in[1];
    const float* loc2   = (const float*)d_in[2];
    const float* scale2 = (const float*)d_in[3];
    float* out = (float*)d_out;

    // workspace layout (floats); total ~16.3 MB
    float* ws   = (float*)d_ws;
    float* A    = ws;                                  // 4096*512
    float* B    = A + (size_t)M_TOT * K2;              // 4096*512
    float* slv  = B + (size_t)M_TOT * K2;              // 4096
    float* cvec = slv + M_TOT;                         // 4096
    float* pm   = cvec + M_TOT;                        // 4096*CS
    float* ps   = pm + (size_t)M_TOT * CS;             // 4096*CS
    float* loss = ps + (size_t)M_TOT * CS;             // 4096

    hipLaunchKernelGGL(prep_kernel, dim3(M_TOT), dim3(256), 0, stream,
                       loc1, scale1, loc2, scale2, A, B, slv, cvec);
    hipLaunchKernelGGL(gemm_lse_kernel, dim3(CS, M_TOT / BM), dim3(256), 0, stream,
                       A, B, slv, cvec, pm, ps);
    hipLaunchKernelGGL(finalize_kernel, dim3(M_TOT / 4), dim3(256), 0, stream,
                       A, B, slv, cvec, pm, ps, loss);
    hipLaunchKernelGGL(mean_kernel, dim3(1), dim3(256), 0, stream, loss, out);
}

// Round 3
// 55.475 us; speedup vs baseline: 5.5457x; 5.5457x over previous
//
#include <hip/hip_runtime.h>
#include <hip/hip_bf16.h>
#include <math.h>

#define N_HALF 2048
#define M_TOT  4096
#define D_DIM  256
#define K2     512
#define NBLK   32            // M_TOT / 128 column blocks
#define KB     16            // K2 / 32 k-steps
#define TILE_BYTES 8192      // 128 rows * 32 k * 2 B

typedef __attribute__((ext_vector_type(8))) short bf16x8;
typedef __attribute__((ext_vector_type(4))) float f32x4;

static __device__ __forceinline__ unsigned short f2bf(float x) {
    union { __hip_bfloat16 h; unsigned short u; } cv;
    cv.h = __float2bfloat16(x);
    return cv.u;
}

static __device__ __forceinline__ void gll16(const void* g, void* l) {
    __builtin_amdgcn_global_load_lds(
        (const __attribute__((address_space(1))) unsigned int*)g,
        (__attribute__((address_space(3))) unsigned int*)l, 16, 0, 0);
}

// ---------------------------------------------------------------------------
// Kernel 1: build bf16 GEMM operands (pre-swizzled, tile-major) + row scalars.
//   A[i] = [mu^2+var , -2*mu],  B[j] = [1/var , mu/var]   (each K=512)
//   Global layout: tiles (rowblk, kblk) of 128x32 bf16, 8192 B each, with
//   16B slot index XOR-swizzled: slot' = slot ^ ((r>>1)&3). A linear
//   global_load_lds copy then yields the swizzled LDS image directly.
// ---------------------------------------------------------------------------
__global__ __launch_bounds__(256) void prep_kernel(
        const float* __restrict__ loc1, const float* __restrict__ scale1,
        const float* __restrict__ loc2, const float* __restrict__ scale2,
        unsigned short* __restrict__ Ab, unsigned short* __restrict__ Bb,
        float* __restrict__ slv, float* __restrict__ cvec) {
    __shared__ float Arow[512], Brow[512], s1[256], s2[256];
    const int i = blockIdx.x, t = threadIdx.x;
    float mu, var;
    if (i < N_HALF) { mu = loc1[i * D_DIM + t];            var = scale1[i * D_DIM + t]; }
    else            { mu = loc2[(i - N_HALF) * D_DIM + t]; var = scale2[(i - N_HALF) * D_DIM + t]; }
    const float iv = 1.0f / var;
    Arow[t]       = mu * mu + var;
    Arow[t + 256] = -2.0f * mu;
    Brow[t]       = iv;
    Brow[t + 256] = mu * iv;
    s1[t] = logf(var);
    s2[t] = mu * mu * iv;
    __syncthreads();
    for (int off = 128; off > 0; off >>= 1) {
        if (t < off) { s1[t] += s1[t + off]; s2[t] += s2[t + off]; }
        __syncthreads();
    }
    if (t == 0) { slv[i] = s1[0]; cvec[i] = s2[0]; }

    if (t < 128) {
        const int tt = t & 63;                 // 64 slots of 8 bf16 per row
        const float* src = (t < 64) ? Arow : Brow;
        unsigned short* dst = (t < 64) ? Ab : Bb;
        const int k0   = tt * 8;
        const int by   = i >> 7, r = i & 127;
        const int kb   = k0 >> 5;
        const int slot = (k0 >> 3) & 3;
        const int sl   = slot ^ ((r >> 1) & 3);
        union { unsigned short u[8]; uint4 v; } pk;
        #pragma unroll
        for (int j = 0; j < 8; ++j) pk.u[j] = f2bf(src[k0 + j]);
        char* base = (char*)dst + (size_t)(by * KB + kb) * TILE_BYTES + r * 64 + sl * 16;
        *(uint4*)base = pk.v;
    }
}

// ---------------------------------------------------------------------------
// Kernel 2: bf16 MFMA GEMM (128x128 tile, 4 waves 2x2, BK=32, K=512) with
// fused online-logsumexp epilogue. Writes (m,s) per (row, colblock).
// sim[i,j] = 5*dot(A_i,B_j) + colv[j] - 5*slv[i]; diagonal excluded.
// ---------------------------------------------------------------------------
__global__ __launch_bounds__(256) void gemm_lse_kernel(
        const unsigned short* __restrict__ Ab, const unsigned short* __restrict__ Bb,
        const float* __restrict__ slv, const float* __restrict__ cvec,
        float* __restrict__ pm, float* __restrict__ ps) {
    __shared__ __align__(16) char smem[16384];
    const int t = threadIdx.x;
    const int lane = t & 63, wid = t >> 6;
    const int bx = blockIdx.x, by = blockIdx.y;
    const int wrow = wid >> 1, wcol = wid & 1;
    const int fr = lane & 15, g = lane >> 4;

    // swizzled LDS read offsets (one 16B slot per fragment)
    int a_off[4], b_off[4];
    #pragma unroll
    for (int fm = 0; fm < 4; ++fm) {
        const int row = wrow * 64 + fm * 16 + fr;
        a_off[fm] = row * 64 + ((g ^ ((row >> 1) & 3)) << 4);
    }
    #pragma unroll
    for (int fn = 0; fn < 4; ++fn) {
        const int row = wcol * 64 + fn * 16 + fr;
        b_off[fn] = 8192 + row * 64 + ((g ^ ((row >> 1) & 3)) << 4);
    }

    f32x4 acc[4][4];
    #pragma unroll
    for (int i = 0; i < 4; ++i)
        #pragma unroll
        for (int j = 0; j < 4; ++j) acc[i][j] = (f32x4){0.f, 0.f, 0.f, 0.f};

    const char* gA = (const char*)Ab + (size_t)by * KB * TILE_BYTES;
    const char* gB = (const char*)Bb + (size_t)bx * KB * TILE_BYTES;

    for (int kk = 0; kk < KB; ++kk) {
        const char* tA = gA + kk * TILE_BYTES;
        const char* tB = gB + kk * TILE_BYTES;
        // stage 16 KB (A-tile + B-tile), 4 chunks per wave, linear dest
        gll16(tA + wid * 1024 + lane * 16,        smem + wid * 1024);
        gll16(tA + 4096 + wid * 1024 + lane * 16, smem + 4096 + wid * 1024);
        gll16(tB + wid * 1024 + lane * 16,        smem + 8192 + wid * 1024);
        gll16(tB + 4096 + wid * 1024 + lane * 16, smem + 12288 + wid * 1024);
        __syncthreads();   // drains vmcnt -> tiles resident
        bf16x8 af[4], bfr[4];
        #pragma unroll
        for (int fm = 0; fm < 4; ++fm) af[fm] = *(const bf16x8*)(smem + a_off[fm]);
        #pragma unroll
        for (int fn = 0; fn < 4; ++fn) bfr[fn] = *(const bf16x8*)(smem + b_off[fn]);
        #pragma unroll
        for (int fm = 0; fm < 4; ++fm)
            #pragma unroll
            for (int fn = 0; fn < 4; ++fn)
                acc[fm][fn] = __builtin_amdgcn_mfma_f32_16x16x32_bf16(
                    af[fm], bfr[fn], acc[fm][fn], 0, 0, 0);
        __syncthreads();   // all reads done before next overwrite
    }

    // ---- fused online-LSE epilogue over this 128x128 sim block ----
    float colv[4]; int gcol[4];
    #pragma unroll
    for (int fn = 0; fn < 4; ++fn) {
        const int c = bx * 128 + wcol * 64 + fn * 16 + fr;
        gcol[fn] = c;
        colv[fn] = 5.0f * (slv[c] + cvec[c]) - 1280.0f;   // 5*(slv+cvec-256)
    }
    float* redm = (float*)smem;            // [128][2]
    float* reds = (float*)(smem + 1024);   // [128][2]

    #pragma unroll
    for (int fm = 0; fm < 4; ++fm) {
        #pragma unroll
        for (int q = 0; q < 4; ++q) {
            const int rloc = wrow * 64 + fm * 16 + g * 4 + q;
            const int grow = by * 128 + rloc;
            const float rv = 5.0f * slv[grow];
            float v[4];
            #pragma unroll
            for (int fn = 0; fn < 4; ++fn) {
                const float x = 5.0f * acc[fm][fn][q] + colv[fn] - rv;
                v[fn] = (grow == gcol[fn]) ? -3.0e38f : x;
            }
            float m = fmaxf(fmaxf(v[0], v[1]), fmaxf(v[2], v[3]));
            float s = __expf(v[0] - m) + __expf(v[1] - m) + __expf(v[2] - m) + __expf(v[3] - m);
            #pragma unroll
            for (int off = 1; off < 16; off <<= 1) {
                const float om = __shfl_xor(m, off, 64);
                const float os = __shfl_xor(s, off, 64);
                const float nm = fmaxf(m, om);
                s = s * __expf(m - nm) + os * __expf(om - nm);
                m = nm;
            }
            if (fr == 0) { redm[rloc * 2 + wcol] = m; reds[rloc * 2 + wcol] = s; }
        }
    }
    __syncthreads();
    if (t < 128) {
        const float m0 = redm[t * 2], m1 = redm[t * 2 + 1];
        const float s0 = reds[t * 2], s1v = reds[t * 2 + 1];
        const float m = fmaxf(m0, m1);
        const float s = s0 * __expf(m0 - m) + s1v * __expf(m1 - m);
        pm[(size_t)(by * 128 + t) * NBLK + bx] = m;
        ps[(size_t)(by * 128 + t) * NBLK + bx] = s;
    }
}

// ---------------------------------------------------------------------------
// Kernel 3: per-row finalize. Combine 32 (m,s) partials -> lse; exact fp32
// pos term from raw inputs; loss[i] = lse - sim_pos.
// NOTE: d below is the FULL quadratic sum_d ((mu_i-mu_j)^2+var_i)/var_j,
// which already includes the c_j term — do NOT add cvec[j] again.
// ---------------------------------------------------------------------------
__global__ __launch_bounds__(256) void finalize_kernel(
        const float* __restrict__ loc1, const float* __restrict__ scale1,
        const float* __restrict__ loc2, const float* __restrict__ scale2,
        const float* __restrict__ slv, const float* __restrict__ cvec,
        const float* __restrict__ pm, const float* __restrict__ ps,
        float* __restrict__ loss) {
    const int t = threadIdx.x, w = t >> 6, lane = t & 63;
    const int i = blockIdx.x * 4 + w;
    const int j = (i < N_HALF) ? i + N_HALF : i - N_HALF;
    const float* mui_p  = (i < N_HALF) ? loc1 + (size_t)i * D_DIM   : loc2 + (size_t)(i - N_HALF) * D_DIM;
    const float* vari_p = (i < N_HALF) ? scale1 + (size_t)i * D_DIM : scale2 + (size_t)(i - N_HALF) * D_DIM;
    const float* muj_p  = (j < N_HALF) ? loc1 + (size_t)j * D_DIM   : loc2 + (size_t)(j - N_HALF) * D_DIM;
    const float* varj_p = (j < N_HALF) ? scale1 + (size_t)j * D_DIM : scale2 + (size_t)(j - N_HALF) * D_DIM;

    const float4 mi = *(const float4*)(mui_p  + lane * 4);
    const float4 vi = *(const float4*)(vari_p + lane * 4);
    const float4 mj = *(const float4*)(muj_p  + lane * 4);
    const float4 vj = *(const float4*)(varj_p + lane * 4);
    float d = 0.0f;
    { float dx = mi.x - mj.x; d += (dx * dx + vi.x) / vj.x; }
    { float dx = mi.y - mj.y; d += (dx * dx + vi.y) / vj.y; }
    { float dx = mi.z - mj.z; d += (dx * dx + vi.z) / vj.z; }
    { float dx = mi.w - mj.w; d += (dx * dx + vi.w) / vj.w; }
    #pragma unroll
    for (int off = 1; off < 64; off <<= 1) d += __shfl_xor(d, off, 64);

    float m = (lane < NBLK) ? pm[(size_t)i * NBLK + lane] : -3.0e38f;
    float s = (lane < NBLK) ? ps[(size_t)i * NBLK + lane] : 0.0f;
    #pragma unroll
    for (int off = 1; off < NBLK; off <<= 1) {
        const float om = __shfl_xor(m, off, 64);
        const float os = __shfl_xor(s, off, 64);
        const float nm = fmaxf(m, om);
        s = s * __expf(m - nm) + os * __expf(om - nm);
        m = nm;
    }
    if (lane == 0) {
        const float lse = m + logf(s);
        const float simpos = 5.0f * (slv[j] - slv[i] - 256.0f + d);   // d already includes c_j
        loss[i] = lse - simpos;
    }
}

// ---------------------------------------------------------------------------
// Kernel 4: mean over M rows -> d_out[0]
// ---------------------------------------------------------------------------
__global__ __launch_bounds__(256) void mean_kernel(const float* __restrict__ loss,
                                                   float* __restrict__ out) {
    __shared__ float sm[256];
    const int t = threadIdx.x;
    float acc = 0.0f;
    for (int k = t; k < M_TOT; k += 256) acc += loss[k];
    sm[t] = acc;
    __syncthreads();
    for (int off = 128; off > 0; off >>= 1) {
        if (t < off) sm[t] += sm[t + off];
        __syncthreads();
    }
    if (t == 0) out[0] = sm[0] * (1.0f / (float)M_TOT);
}

// ---------------------------------------------------------------------------
extern "C" void kernel_launch(void* const* d_in, const int* in_sizes, int n_in,
                              void* d_out, int out_size, void* d_ws, size_t ws_size,
                              hipStream_t stream) {
    const float* loc1   = (const float*)d_in[0];
    const float* scale1 = (const float*)d_in[1];
    const float* loc2   = (const float*)d_in[2];
    const float* scale2 = (const float*)d_in[3];
    float* out = (float*)d_out;

    char* ws = (char*)d_ws;
    unsigned short* Ab = (unsigned short*)ws;                          // 4 MB
    unsigned short* Bb = (unsigned short*)(ws + (size_t)4 * 1024 * 1024);  // 4 MB
    float* slv  = (float*)(ws + (size_t)8 * 1024 * 1024);              // 16 KB
    float* cvec = slv + M_TOT;
    float* pm   = cvec + M_TOT;                                        // 512 KB
    float* ps   = pm + (size_t)M_TOT * NBLK;                           // 512 KB
    float* loss = ps + (size_t)M_TOT * NBLK;                           // 16 KB

    hipLaunchKernelGGL(prep_kernel, dim3(M_TOT), dim3(256), 0, stream,
                       loc1, scale1, loc2, scale2, Ab, Bb, slv, cvec);
    hipLaunchKernelGGL(gemm_lse_kernel, dim3(NBLK, NBLK), dim3(256), 0, stream,
                       Ab, Bb, slv, cvec, pm, ps);
    hipLaunchKernelGGL(finalize_kernel, dim3(M_TOT / 4), dim3(256), 0, stream,
                       loc1, scale1, loc2, scale2, slv, cvec, pm, ps, loss);
    hipLaunchKernelGGL(mean_kernel, dim3(1), dim3(256), 0, stream, loss, out);
}